// Round 1
// baseline (276.611 us; speedup 1.0000x reference)
//
#include <hip/hip_runtime.h>

#define LOG2E 1.4426950408889634f

typedef float  f32x4 __attribute__((ext_vector_type(4)));
typedef int    i32x4 __attribute__((ext_vector_type(4)));
typedef short  s16x8 __attribute__((ext_vector_type(8)));
typedef unsigned long long u64x2 __attribute__((ext_vector_type(2)));

static __device__ __forceinline__ float exp2_fast(float x) {
#if __has_builtin(__builtin_amdgcn_exp2f)
    return __builtin_amdgcn_exp2f(x);
#else
    return exp2f(x);
#endif
}
static __device__ __forceinline__ unsigned short bf16_rne(float f) {
    unsigned u = __float_as_uint(f);
    u += 0x7FFFu + ((u >> 16) & 1u);
    return (unsigned short)(u >> 16);
}
// 1-bit signed bitfield extract -> 0 or 0xFFFFFFFF
static __device__ __forceinline__ int sbfe1(unsigned w, int pos) {
#if __has_builtin(__builtin_amdgcn_sbfe)
    return __builtin_amdgcn_sbfe((int)w, pos, 1);
#else
    return (int)(w << (31 - pos)) >> 31;
#endif
}
// pack hi16(u0) | hi16(u1)<<16 in one v_perm
static __device__ __forceinline__ unsigned pack_hi16(unsigned u1, unsigned u0) {
#if __has_builtin(__builtin_amdgcn_perm)
    return __builtin_amdgcn_perm(u1, u0, 0x07060302u);
#else
    return (u0 >> 16) | (u1 & 0xFFFF0000u);
#endif
}

// ---------------------------------------------------------------------------
// K0 (fused preprocessing): adj -> bitmask (4 elem/thread, ballot), x -> bf16,
// W -> bf16 transposed Wt[h][o][K], Mx slots init to encoded -inf.
// grid = 16384 (bits) + 2048 (x) + 449 (W + Mx) = 18881 blocks.
// ---------------------------------------------------------------------------
__global__ __launch_bounds__(256) void prep_all(
    const float* __restrict__ xf, const int* __restrict__ adj,
    const float* __restrict__ W0, const float* __restrict__ W1,
    const float* __restrict__ W2,
    unsigned short* __restrict__ xc, unsigned long long* __restrict__ bits,
    unsigned short* __restrict__ W0t, unsigned short* __restrict__ W1t,
    unsigned short* __restrict__ W2t, unsigned* __restrict__ MxU)
{
    const int b = blockIdx.x, tid = threadIdx.x;
    if (b < 16384) {                        // adj -> bits, 1024 elem/block
        const int w = tid >> 6, lane = tid & 63;
        const int base = b * 1024 + w * 256;
        unsigned long long m[4];
#pragma unroll
        for (int r = 0; r < 4; ++r)
            m[r] = __ballot(adj[base + r * 64 + lane] != 0);
        if (lane == 0) {
            u64x2 lo = {m[0], m[1]}, hi = {m[2], m[3]};
            *(u64x2*)(bits + (base >> 6))     = lo;
            *(u64x2*)(bits + (base >> 6) + 2) = hi;
        }
    } else if (b < 18432) {                 // x f32 -> bf16
        int i = (b - 16384) * 256 + tid;
        xc[i] = bf16_rne(xf[i]);
    } else {                                // W transpose + Mx init
        int gid = (b - 18432) * 256 + tid;
        if (gid < 32768) {                  // W0: (4,128,64)
            int h = gid >> 13, d = (gid >> 6) & 127, o = gid & 63;
            W0t[(h * 64 + o) * 128 + d] = bf16_rne(W0[gid]);
        } else if (gid < 98304) {           // W1: (4,256,64)
            int g = gid - 32768;
            int h = g >> 14, d = (g >> 6) & 255, o = g & 63;
            W1t[(h * 64 + o) * 256 + d] = bf16_rne(W1[g]);
        } else if (gid < 114688) {          // W2: (1,256,64)
            int g = gid - 98304;
            int d = g >> 6, o = g & 63;
            W2t[o * 256 + d] = bf16_rne(W2[g]);
        } else if (gid < 114700) {          // Mx[12] = encoded -inf
            MxU[gid - 114688] = 0x007FFFFFu;
        }
    }
}

// ---------------------------------------------------------------------------
// K2 (per layer): h = X @ W (MFMA 16x16x32 bf16) -> hT[h][o][n] (bf16),
// fused el2/er2 = (h.a_l)*log2e, (h.a_r)*log2e, and per-head max of er2
// via order-independent encoded atomicMax (replaces hmax kernel).
// Wave = 16 rows x 64 cols, block = 4 waves, grid = (N/64, H).
// ---------------------------------------------------------------------------
__global__ __launch_bounds__(256) void gemm_elr(
    const unsigned short* __restrict__ X, int K,
    const unsigned short* __restrict__ Wt,   // [H][64][K] bf16
    const float* __restrict__ a,             // [H][128] f32 (a_l | a_r)
    unsigned short* __restrict__ hT,         // [H][64][4096]
    float* __restrict__ el2, float* __restrict__ er2,   // [H][4096]
    unsigned* __restrict__ MxU)              // [H] encoded max(er2)
{
    const int lane = threadIdx.x & 63, w = threadIdx.x >> 6;
    const int c = lane & 15, q = lane >> 4;
    const int h = blockIdx.y;
    const int nb = blockIdx.x * 64 + w * 16;
    const unsigned short* xrow = X + (size_t)(nb + c) * K + q * 8;
    const unsigned short* wb   = Wt + ((size_t)h * 64 + c) * K + q * 8;

    f32x4 acc[4] = {{0,0,0,0},{0,0,0,0},{0,0,0,0},{0,0,0,0}};
    for (int kk = 0; kk < K; kk += 32) {
        s16x8 af = *(const s16x8*)(xrow + kk);
#pragma unroll
        for (int j = 0; j < 4; ++j) {
            s16x8 bf = *(const s16x8*)(wb + (size_t)(j * 16) * K + kk);
            acc[j] = __builtin_amdgcn_mfma_f32_16x16x32_bf16(af, bf, acc[j], 0, 0, 0);
        }
    }
    // C/D layout: col = lane&15, row = q*4 + reg  ->  hT[h][o][n]
#pragma unroll
    for (int j = 0; j < 4; ++j) {
        unsigned d0 = (unsigned)bf16_rne(acc[j][0]) | ((unsigned)bf16_rne(acc[j][1]) << 16);
        unsigned d1 = (unsigned)bf16_rne(acc[j][2]) | ((unsigned)bf16_rne(acc[j][3]) << 16);
        unsigned short* dst = hT + ((size_t)h * 64 + j * 16 + c) * 4096 + nb + q * 4;
        ((unsigned*)dst)[0] = d0;
        ((unsigned*)dst)[1] = d1;
    }
    // el/er: dot C-tile rows with a_l/a_r, butterfly-reduce over the 16 c-lanes
    const float* ab = a + h * 128;
    float elr[4] = {0,0,0,0}, err[4] = {0,0,0,0};
#pragma unroll
    for (int j = 0; j < 4; ++j) {
        float al = ab[j * 16 + c];
        float ar = ab[64 + j * 16 + c];
#pragma unroll
        for (int r = 0; r < 4; ++r) {
            elr[r] = fmaf(al, acc[j][r], elr[r]);
            err[r] = fmaf(ar, acc[j][r], err[r]);
        }
    }
#pragma unroll
    for (int m = 1; m <= 8; m <<= 1) {
#pragma unroll
        for (int r = 0; r < 4; ++r) {
            elr[r] += __shfl_xor(elr[r], m, 64);
            err[r] += __shfl_xor(err[r], m, 64);
        }
    }
    if (c == 0) {
#pragma unroll
        for (int r = 0; r < 4; ++r) {
            int n = nb + q * 4 + r;
            el2[h * 4096 + n] = elr[r] * LOG2E;
            er2[h * 4096 + n] = err[r] * LOG2E;
        }
    }
    // per-head running max of er2 (order-independent -> deterministic)
    float mm = fmaxf(fmaxf(err[0], err[1]), fmaxf(err[2], err[3]));
    mm = fmaxf(mm, __shfl_xor(mm, 16, 64));
    mm = fmaxf(mm, __shfl_xor(mm, 32, 64));
    if (lane == 0) {
        unsigned u = __float_as_uint(mm * LOG2E);
        unsigned key = (u & 0x80000000u) ? ~u : (u | 0x80000000u);
        atomicMax(MxU + h, key);
    }
}

// ---------------------------------------------------------------------------
// K3 (per layer): fused masked-softmax attention, factorized exp2:
//   p[n][m] = max(Al[n]*Ar[m], Bl[n]*Br[m]) & adjbit      (p <= 1)
// where Al=exp2(el+M2-C2), Bl=exp2(0.2(el+M2)-C2) per row and
//       Ar=exp2(er-M2),    Br=exp2(0.2(er-M2))    per column.
// LDS hT tile 64(o) x 256(m) bf16, stride 256 + XOR swizzle (o&7) on 16B
// groups -> 2-way max bank aliasing on ds_read_b128 (free).
// grid = (64, H, KS), block = 4 waves x 16 rows.
// ---------------------------------------------------------------------------
__global__ __launch_bounds__(256) void att_kernel(
    const unsigned short* __restrict__ hT,
    const float* __restrict__ el2g, const float* __restrict__ er2g,
    const unsigned* __restrict__ MxU,
    const unsigned long long* __restrict__ bits,
    float* __restrict__ accP, float* __restrict__ lP,
    int H, int KPS, int HO)
{
    __shared__ unsigned short ldsH[64 * 256];
    __shared__ float ldsE[512];              // [m][{Ar,Br}]
    const int tid = threadIdx.x;
    const int lane = tid & 63, w = tid >> 6;
    const int c = lane & 15, q = lane >> 4, q8 = q * 8;
    const int h = blockIdx.y, ks = blockIdx.z;
    const int nb = blockIdx.x * 64 + w * 16;
    const int rowA = nb + c;

    unsigned kM = MxU[h];
    float M2 = __uint_as_float((kM & 0x80000000u) ? (kM & 0x7FFFFFFFu) : ~kM);
    float e2 = el2g[h * 4096 + rowA];
    float xx = e2 + M2;
    float C2 = fmaxf(xx, 0.2f * xx);         // C2 >= all scores of this row
    const float Al = exp2_fast(xx - C2);
    const float Bl = exp2_fast(fmaf(0.2f, xx, -C2));

    const char* bitrow = (const char*)bits + (size_t)rowA * 512 + (size_t)(KPS >> 3) * ks;

    s16x8 ones = {0,0,0,0,0,0,0,0};
    if (c == 0) {
#pragma unroll
        for (int i = 0; i < 8; ++i) ones[i] = (short)0x3F80;   // bf16 1.0, col 0
    }
    f32x4 acc[4] = {{0,0,0,0},{0,0,0,0},{0,0,0,0},{0,0,0,0}};
    f32x4 accl = {0,0,0,0};

    const unsigned short* hTh = hT + (size_t)h * 64 * 4096;
    const float* erh = er2g + h * 4096;
    const int tiles = KPS >> 8;

    for (int t = 0; t < tiles; ++t) {
        const int mabs = ks * KPS + t * 256;
#pragma unroll
        for (int i = 0; i < 8; ++i) {
            int cidx = i * 256 + tid;
            int o = cidx >> 5, seg = cidx & 31;
            i32x4 v = *(const i32x4*)(hTh + (size_t)o * 4096 + mabs + seg * 8);
            *(i32x4*)(ldsH + o * 256 + ((seg ^ (o & 7)) << 3)) = v;
        }
        {   // per-column factors (2 exp2 per column instead of 1 per element)
            float er = erh[mabs + tid] - M2;
            ldsE[2 * tid]     = exp2_fast(er);
            ldsE[2 * tid + 1] = exp2_fast(0.2f * er);
        }
        __syncthreads();

        i32x4 b0 = *(const i32x4*)(bitrow + t * 32);
        i32x4 b1 = *(const i32x4*)(bitrow + t * 32 + 16);
        int bw[8] = {b0[0], b0[1], b0[2], b0[3], b1[0], b1[1], b1[2], b1[3]};

#pragma unroll
        for (int cc = 0; cc < 8; ++cc) {
            const int kl = cc * 32 + q8;
            const f32x4* ep = (const f32x4*)(ldsE + 2 * kl);   // broadcast reads
            f32x4 ev0 = ep[0], ev1 = ep[1], ev2 = ep[2], ev3 = ep[3];
            const unsigned word = (unsigned)bw[cc];
            unsigned pd[4];
#pragma unroll
            for (int jj = 0; jj < 4; ++jj) {
                f32x4 ev = (jj == 0) ? ev0 : (jj == 1) ? ev1 : (jj == 2) ? ev2 : ev3;
                float p0 = fmaxf(Al * ev[0], Bl * ev[1]);
                float p1 = fmaxf(Al * ev[2], Bl * ev[3]);
                unsigned u0 = __float_as_uint(p0) & (unsigned)sbfe1(word, q8 + 2 * jj);
                unsigned u1 = __float_as_uint(p1) & (unsigned)sbfe1(word, q8 + 2 * jj + 1);
                pd[jj] = pack_hi16(u1, u0);   // truncate-pack 2 bf16
            }
            union { unsigned u[4]; s16x8 s; } afu;
            afu.u[0] = pd[0]; afu.u[1] = pd[1]; afu.u[2] = pd[2]; afu.u[3] = pd[3];
            s16x8 af = afu.s;
            const int klx = kl ^ ((c & 7) << 3);
            const unsigned short* lb = ldsH + c * 256 + klx;
#pragma unroll
            for (int j = 0; j < 4; ++j) {
                s16x8 bf = *(const s16x8*)(lb + (size_t)(j * 16) * 256);
                acc[j] = __builtin_amdgcn_mfma_f32_16x16x32_bf16(af, bf, acc[j], 0, 0, 0);
            }
            accl = __builtin_amdgcn_mfma_f32_16x16x32_bf16(af, ones, accl, 0, 0, 0);
        }
        __syncthreads();
    }
    // denominator: column 0 of accl (lanes c==0), rows q*4+r
    float ls[4];
#pragma unroll
    for (int r = 0; r < 4; ++r) ls[r] = __shfl(accl[r], lane & 48, 64);

    float* ap = accP + ((size_t)ks * 4096 + nb + q * 4) * HO + h * 64 + c;
#pragma unroll
    for (int r = 0; r < 4; ++r)
#pragma unroll
        for (int j = 0; j < 4; ++j)
            ap[(size_t)r * HO + j * 16] = acc[j][r];
    if (c == 0) {
#pragma unroll
        for (int r = 0; r < 4; ++r)
            lP[((size_t)ks * H + h) * 4096 + nb + q * 4 + r] = ls[r];
    }
}

// ---------------------------------------------------------------------------
// K4: combine key-split partials, divide, optional ELU.
// Internal layers write bf16 (outb); final layer writes f32 (outf).
// ---------------------------------------------------------------------------
__global__ __launch_bounds__(256) void comb_kernel(
    const float* __restrict__ accP, const float* __restrict__ lP,
    unsigned short* __restrict__ outb, float* __restrict__ outf,
    int KS, int H, int lgHO, int do_elu)
{
    const int idx = blockIdx.x * 256 + threadIdx.x;
    const int HO = 1 << lgHO;
    const int n = idx >> lgHO, col = idx & (HO - 1), h = col >> 6;
    float s = 0.f, l = 0.f;
    for (int ks = 0; ks < KS; ++ks) {
        s += accP[((size_t)ks * 4096 + n) * HO + col];
        l += lP[((size_t)ks * H + h) * 4096 + n];
    }
    float v = s / l;
    if (do_elu && v < 0.f) v = exp2_fast(v * LOG2E) - 1.f;
    if (outf) outf[idx] = v;
    else      outb[idx] = bf16_rne(v);
}

// ---------------------------------------------------------------------------
extern "C" void kernel_launch(void* const* d_in, const int* in_sizes, int n_in,
                              void* d_out, int out_size, void* d_ws, size_t ws_size,
                              hipStream_t stream)
{
    (void)in_sizes; (void)n_in; (void)out_size; (void)ws_size;
    const float* x   = (const float*)d_in[0];
    const int*   adj = (const int*)d_in[1];
    const float* W0  = (const float*)d_in[2];
    const float* a0  = (const float*)d_in[3];
    const float* W1  = (const float*)d_in[4];
    const float* a1  = (const float*)d_in[5];
    const float* W2  = (const float*)d_in[6];
    const float* a2  = (const float*)d_in[7];

    char* p = (char*)d_ws;                                   // 15.5 MB used
    unsigned long long* bits = (unsigned long long*)(p + 0x000000);  // 2 MB
    unsigned short* hT  = (unsigned short*)(p + 0x200000);           // 2 MB
    unsigned short* X12 = (unsigned short*)(p + 0x400000);           // 2 MB
    unsigned short* Xc  = (unsigned short*)(p + 0x600000);           // 1 MB
    unsigned short* W0t = (unsigned short*)(p + 0x700000);           // 64 KB
    unsigned short* W1t = (unsigned short*)(p + 0x710000);           // 128 KB
    unsigned short* W2t = (unsigned short*)(p + 0x730000);           // 32 KB
    float*    el2  = (float*)(p + 0x738000);                         // 64 KB
    float*    er2  = (float*)(p + 0x748000);                         // 64 KB
    unsigned* MxU  = (unsigned*)(p + 0x758000);                      // 48 B (3 layers x 4)
    float*    accP = (float*)(p + 0x760000);                         // 8 MB
    float*    lP   = (float*)(p + 0xF60000);                         // 128 KB

    prep_all<<<18881, 256, 0, stream>>>(x, adj, W0, W1, W2, Xc, bits,
                                        W0t, W1t, W2t, MxU);

    // layer 0: K=128, H=4
    gemm_elr<<<dim3(64, 4), 256, 0, stream>>>(Xc, 128, W0t, a0, hT, el2, er2, MxU + 0);
    att_kernel<<<dim3(64, 4, 2), 256, 0, stream>>>(hT, el2, er2, MxU + 0, bits, accP, lP, 4, 2048, 256);
    comb_kernel<<<4096, 256, 0, stream>>>(accP, lP, X12, nullptr, 2, 4, 8, 1);

    // layer 1: K=256, H=4
    gemm_elr<<<dim3(64, 4), 256, 0, stream>>>(X12, 256, W1t, a1, hT, el2, er2, MxU + 4);
    att_kernel<<<dim3(64, 4, 2), 256, 0, stream>>>(hT, el2, er2, MxU + 4, bits, accP, lP, 4, 2048, 256);
    comb_kernel<<<4096, 256, 0, stream>>>(accP, lP, X12, nullptr, 2, 4, 8, 1);

    // layer 2: K=256, H=1, output f32 (no ELU)
    gemm_elr<<<dim3(64, 1), 256, 0, stream>>>(X12, 256, W2t, a2, hT, el2, er2, MxU + 8);
    att_kernel<<<dim3(64, 1, 4), 256, 0, stream>>>(hT, el2, er2, MxU + 8, bits, accP, lP, 1, 1024, 64);
    comb_kernel<<<1024, 256, 0, stream>>>(accP, lP, nullptr, (float*)d_out, 4, 1, 6, 0);
}

// Round 2
// 226.051 us; speedup vs baseline: 1.2237x; 1.2237x over previous
//
#include <hip/hip_runtime.h>

#define LOG2E 1.4426950408889634f

typedef float  f32x4 __attribute__((ext_vector_type(4)));
typedef int    i32x4 __attribute__((ext_vector_type(4)));
typedef short  s16x8 __attribute__((ext_vector_type(8)));
typedef unsigned long long u64x2 __attribute__((ext_vector_type(2)));

static __device__ __forceinline__ float exp2_fast(float x) {
#if __has_builtin(__builtin_amdgcn_exp2f)
    return __builtin_amdgcn_exp2f(x);
#else
    return exp2f(x);
#endif
}
static __device__ __forceinline__ unsigned short bf16_rne(float f) {
    unsigned u = __float_as_uint(f);
    u += 0x7FFFu + ((u >> 16) & 1u);
    return (unsigned short)(u >> 16);
}
// 1-bit signed bitfield extract -> 0 or 0xFFFFFFFF
static __device__ __forceinline__ int sbfe1(unsigned w, int pos) {
#if __has_builtin(__builtin_amdgcn_sbfe)
    return __builtin_amdgcn_sbfe((int)w, pos, 1);
#else
    return (int)(w << (31 - pos)) >> 31;
#endif
}
// pack hi16(u0) | hi16(u1)<<16 in one v_perm
static __device__ __forceinline__ unsigned pack_hi16(unsigned u1, unsigned u0) {
#if __has_builtin(__builtin_amdgcn_perm)
    return __builtin_amdgcn_perm(u1, u0, 0x07060302u);
#else
    return (u0 >> 16) | (u1 & 0xFFFF0000u);
#endif
}

// ---------------------------------------------------------------------------
// K0 (fused preprocessing): adj -> bitmask (4 elem/thread, ballot), x -> bf16,
// W -> bf16 transposed Wt[h][o][K], Mx slots init to encoded -inf.
// ---------------------------------------------------------------------------
__global__ __launch_bounds__(256) void prep_all(
    const float* __restrict__ xf, const int* __restrict__ adj,
    const float* __restrict__ W0, const float* __restrict__ W1,
    const float* __restrict__ W2,
    unsigned short* __restrict__ xc, unsigned long long* __restrict__ bits,
    unsigned short* __restrict__ W0t, unsigned short* __restrict__ W1t,
    unsigned short* __restrict__ W2t, unsigned* __restrict__ MxU)
{
    const int b = blockIdx.x, tid = threadIdx.x;
    if (b < 16384) {                        // adj -> bits, 1024 elem/block
        const int w = tid >> 6, lane = tid & 63;
        const int base = b * 1024 + w * 256;
        unsigned long long m[4];
#pragma unroll
        for (int r = 0; r < 4; ++r)
            m[r] = __ballot(adj[base + r * 64 + lane] != 0);
        if (lane == 0) {
            u64x2 lo = {m[0], m[1]}, hi = {m[2], m[3]};
            *(u64x2*)(bits + (base >> 6))     = lo;
            *(u64x2*)(bits + (base >> 6) + 2) = hi;
        }
    } else if (b < 18432) {                 // x f32 -> bf16
        int i = (b - 16384) * 256 + tid;
        xc[i] = bf16_rne(xf[i]);
    } else {                                // W transpose + Mx init
        int gid = (b - 18432) * 256 + tid;
        if (gid < 32768) {                  // W0: (4,128,64)
            int h = gid >> 13, d = (gid >> 6) & 127, o = gid & 63;
            W0t[(h * 64 + o) * 128 + d] = bf16_rne(W0[gid]);
        } else if (gid < 98304) {           // W1: (4,256,64)
            int g = gid - 32768;
            int h = g >> 14, d = (g >> 6) & 255, o = g & 63;
            W1t[(h * 64 + o) * 256 + d] = bf16_rne(W1[g]);
        } else if (gid < 114688) {          // W2: (1,256,64)
            int g = gid - 98304;
            int d = g >> 6, o = g & 63;
            W2t[o * 256 + d] = bf16_rne(W2[g]);
        } else if (gid < 114700) {          // Mx[12] = encoded -inf
            MxU[gid - 114688] = 0x007FFFFFu;
        }
    }
}

// ---------------------------------------------------------------------------
// K2 (per layer): h = X @ W (MFMA 16x16x32 bf16) -> hT[h][o][n] (bf16),
// fused el2/er2 and per-head max of er2 via encoded atomicMax.
// ---------------------------------------------------------------------------
__global__ __launch_bounds__(256) void gemm_elr(
    const unsigned short* __restrict__ X, int K,
    const unsigned short* __restrict__ Wt,   // [H][64][K] bf16
    const float* __restrict__ a,             // [H][128] f32 (a_l | a_r)
    unsigned short* __restrict__ hT,         // [H][64][4096]
    float* __restrict__ el2, float* __restrict__ er2,   // [H][4096]
    unsigned* __restrict__ MxU)              // [H] encoded max(er2)
{
    const int lane = threadIdx.x & 63, w = threadIdx.x >> 6;
    const int c = lane & 15, q = lane >> 4;
    const int h = blockIdx.y;
    const int nb = blockIdx.x * 64 + w * 16;
    const unsigned short* xrow = X + (size_t)(nb + c) * K + q * 8;
    const unsigned short* wb   = Wt + ((size_t)h * 64 + c) * K + q * 8;

    f32x4 acc[4] = {{0,0,0,0},{0,0,0,0},{0,0,0,0},{0,0,0,0}};
    for (int kk = 0; kk < K; kk += 32) {
        s16x8 af = *(const s16x8*)(xrow + kk);
#pragma unroll
        for (int j = 0; j < 4; ++j) {
            s16x8 bf = *(const s16x8*)(wb + (size_t)(j * 16) * K + kk);
            acc[j] = __builtin_amdgcn_mfma_f32_16x16x32_bf16(af, bf, acc[j], 0, 0, 0);
        }
    }
    // C/D layout: col = lane&15, row = q*4 + reg  ->  hT[h][o][n]
#pragma unroll
    for (int j = 0; j < 4; ++j) {
        unsigned d0 = (unsigned)bf16_rne(acc[j][0]) | ((unsigned)bf16_rne(acc[j][1]) << 16);
        unsigned d1 = (unsigned)bf16_rne(acc[j][2]) | ((unsigned)bf16_rne(acc[j][3]) << 16);
        unsigned short* dst = hT + ((size_t)h * 64 + j * 16 + c) * 4096 + nb + q * 4;
        ((unsigned*)dst)[0] = d0;
        ((unsigned*)dst)[1] = d1;
    }
    const float* ab = a + h * 128;
    float elr[4] = {0,0,0,0}, err[4] = {0,0,0,0};
#pragma unroll
    for (int j = 0; j < 4; ++j) {
        float al = ab[j * 16 + c];
        float ar = ab[64 + j * 16 + c];
#pragma unroll
        for (int r = 0; r < 4; ++r) {
            elr[r] = fmaf(al, acc[j][r], elr[r]);
            err[r] = fmaf(ar, acc[j][r], err[r]);
        }
    }
#pragma unroll
    for (int m = 1; m <= 8; m <<= 1) {
#pragma unroll
        for (int r = 0; r < 4; ++r) {
            elr[r] += __shfl_xor(elr[r], m, 64);
            err[r] += __shfl_xor(err[r], m, 64);
        }
    }
    if (c == 0) {
#pragma unroll
        for (int r = 0; r < 4; ++r) {
            int n = nb + q * 4 + r;
            el2[h * 4096 + n] = elr[r] * LOG2E;
            er2[h * 4096 + n] = err[r] * LOG2E;
        }
    }
    float mm = fmaxf(fmaxf(err[0], err[1]), fmaxf(err[2], err[3]));
    mm = fmaxf(mm, __shfl_xor(mm, 16, 64));
    mm = fmaxf(mm, __shfl_xor(mm, 32, 64));
    if (lane == 0) {
        unsigned u = __float_as_uint(mm * LOG2E);
        unsigned key = (u & 0x80000000u) ? ~u : (u | 0x80000000u);
        atomicMax(MxU + h, key);
    }
}

// ---------------------------------------------------------------------------
// K3 (per layer): fused masked-softmax attention, factorized exp2, now with
// double-buffered async staging (global_load_lds, pre-swizzled source),
// ONE barrier per tile, register prefetch of bits/er, ldsE read prefetch
// one cc ahead, setprio around MFMA clusters.
//   p[n][m] = max(Al[n]*Ar[m], Bl[n]*Br[m]) & adjbit      (p <= 1)
// LDS hT tile 2 x 64(o) x 256(m) bf16, XOR swizzle (o&7) on 16B groups.
// grid = (64, H, KS), block = 4 waves x 16 rows.
// ---------------------------------------------------------------------------
__global__ __launch_bounds__(256) void att_kernel(
    const unsigned short* __restrict__ hT,
    const float* __restrict__ el2g, const float* __restrict__ er2g,
    const unsigned* __restrict__ MxU,
    const unsigned long long* __restrict__ bits,
    float* __restrict__ accP, float* __restrict__ lP,
    int H, int KPS, int HO)
{
    __shared__ unsigned short ldsH[2][64 * 256];
    __shared__ float ldsE[2][512];           // [buf][m][{Ar,Br}]
    const int tid = threadIdx.x;
    const int lane = tid & 63, w = tid >> 6;
    const int c = lane & 15, q = lane >> 4, q8 = q * 8;
    const int h = blockIdx.y, ks = blockIdx.z;
    const int nb = blockIdx.x * 64 + w * 16;
    const int rowA = nb + c;

    unsigned kM = MxU[h];
    float M2 = __uint_as_float((kM & 0x80000000u) ? (kM & 0x7FFFFFFFu) : ~kM);
    float e2 = el2g[h * 4096 + rowA];
    float xx = e2 + M2;
    float C2 = fmaxf(xx, 0.2f * xx);         // C2 >= all scores of this row
    const float Al = exp2_fast(xx - C2);
    const float Bl = exp2_fast(fmaf(0.2f, xx, -C2));

    const char* bitrow = (const char*)bits + (size_t)rowA * 512 + (size_t)(KPS >> 3) * ks;
    const unsigned short* hTh = hT + (size_t)h * 64 * 4096;
    const float* erh = er2g + h * 4096;
    const int tiles = KPS >> 8;
    const int kbase = ks * KPS;

    // DMA stage: LDS dest linear in lane; swizzle applied on the GLOBAL src
    // address (m173) so reads can use the conflict-free XOR layout.
    auto STAGE = [&](int buf, int mabs_) {
#pragma unroll
        for (int i = 0; i < 8; ++i) {
            int cidx = i * 256 + tid;
            int o = cidx >> 5, g = cidx & 31;
            const unsigned short* sp =
                hTh + (size_t)o * 4096 + mabs_ + ((g ^ (o & 7)) << 3);
            unsigned short* dp = &ldsH[buf][(i * 256 + (tid & ~63)) << 3];
            __builtin_amdgcn_global_load_lds(
                (const __attribute__((address_space(1))) void*)sp,
                (__attribute__((address_space(3))) void*)dp, 16, 0, 0);
        }
    };

    s16x8 ones = {0,0,0,0,0,0,0,0};
    if (c == 0) {
#pragma unroll
        for (int i = 0; i < 8; ++i) ones[i] = (short)0x3F80;   // bf16 1.0, col 0
    }
    f32x4 acc[4] = {{0,0,0,0},{0,0,0,0},{0,0,0,0},{0,0,0,0}};
    f32x4 accl = {0,0,0,0};

    // ---- prologue: stage tile 0 (DMA + column factors + bits) ----
    STAGE(0, kbase);
    {
        float ee = erh[kbase + tid] - M2;
        ldsE[0][2 * tid]     = exp2_fast(ee);
        ldsE[0][2 * tid + 1] = exp2_fast(0.2f * ee);
    }
    i32x4 bA = *(const i32x4*)(bitrow);
    i32x4 bB = *(const i32x4*)(bitrow + 16);
    __syncthreads();                         // drains DMA (vmcnt 0)

    for (int t = 0; t < tiles; ++t) {
        const int cur = t & 1, nxt = cur ^ 1;
        const bool more = (t + 1 < tiles);
        const unsigned short* Hc = ldsH[cur];
        const float* Ec = ldsE[cur];

        // prefetch ev for cc=0 (the ldsE broadcast reads carry a measured
        // ~4-cycle bank penalty; keep them one step ahead of their use)
        const f32x4* ep0 = (const f32x4*)(Ec + 2 * q8);
        f32x4 nv0 = ep0[0], nv1 = ep0[1], nv2 = ep0[2], nv3 = ep0[3];

        float ern = 0.f;
        if (more) {
            const int mn = kbase + (t + 1) * 256;
            STAGE(nxt, mn);                  // async, drains at the barrier
            ern = erh[mn + tid];
        }
        int bw[8] = {bA[0], bA[1], bA[2], bA[3], bB[0], bB[1], bB[2], bB[3]};
        if (more) {
            bA = *(const i32x4*)(bitrow + (t + 1) * 32);
            bB = *(const i32x4*)(bitrow + (t + 1) * 32 + 16);
        }

#pragma unroll
        for (int cc = 0; cc < 8; ++cc) {
            f32x4 ev0 = nv0, ev1 = nv1, ev2 = nv2, ev3 = nv3;
            if (cc < 7) {
                const f32x4* epn = (const f32x4*)(Ec + 2 * ((cc + 1) * 32 + q8));
                nv0 = epn[0]; nv1 = epn[1]; nv2 = epn[2]; nv3 = epn[3];
            }
            const int kl = cc * 32 + q8;
            const unsigned word = (unsigned)bw[cc];
            unsigned pd[4];
#pragma unroll
            for (int jj = 0; jj < 4; ++jj) {
                f32x4 ev = (jj == 0) ? ev0 : (jj == 1) ? ev1 : (jj == 2) ? ev2 : ev3;
                float p0 = fmaxf(Al * ev[0], Bl * ev[1]);
                float p1 = fmaxf(Al * ev[2], Bl * ev[3]);
                unsigned u0 = __float_as_uint(p0) & (unsigned)sbfe1(word, q8 + 2 * jj);
                unsigned u1 = __float_as_uint(p1) & (unsigned)sbfe1(word, q8 + 2 * jj + 1);
                pd[jj] = pack_hi16(u1, u0);  // truncate-pack 2 bf16
            }
            union { unsigned u[4]; s16x8 s; } afu;
            afu.u[0] = pd[0]; afu.u[1] = pd[1]; afu.u[2] = pd[2]; afu.u[3] = pd[3];
            s16x8 af = afu.s;
            const int klx = kl ^ ((c & 7) << 3);
            const unsigned short* lb = Hc + c * 256 + klx;
            __builtin_amdgcn_s_setprio(1);
#pragma unroll
            for (int j = 0; j < 4; ++j) {
                s16x8 bf = *(const s16x8*)(lb + (size_t)(j * 16) * 256);
                acc[j] = __builtin_amdgcn_mfma_f32_16x16x32_bf16(af, bf, acc[j], 0, 0, 0);
            }
            accl = __builtin_amdgcn_mfma_f32_16x16x32_bf16(af, ones, accl, 0, 0, 0);
            __builtin_amdgcn_s_setprio(0);
        }

        if (more) {                          // column factors for t+1
            float ee = ern - M2;
            ldsE[nxt][2 * tid]     = exp2_fast(ee);
            ldsE[nxt][2 * tid + 1] = exp2_fast(0.2f * ee);
        }
        __syncthreads();                     // one barrier/tile: drains DMA+LDS
    }

    // denominator: column 0 of accl (lanes c==0), rows q*4+r
    float ls[4];
#pragma unroll
    for (int r = 0; r < 4; ++r) ls[r] = __shfl(accl[r], lane & 48, 64);

    float* ap = accP + ((size_t)ks * 4096 + nb + q * 4) * HO + h * 64 + c;
#pragma unroll
    for (int r = 0; r < 4; ++r)
#pragma unroll
        for (int j = 0; j < 4; ++j)
            ap[(size_t)r * HO + j * 16] = acc[j][r];
    if (c == 0) {
#pragma unroll
        for (int r = 0; r < 4; ++r)
            lP[((size_t)ks * H + h) * 4096 + nb + q * 4 + r] = ls[r];
    }
}

// ---------------------------------------------------------------------------
// K4: combine key-split partials, divide, optional ELU.
// ---------------------------------------------------------------------------
__global__ __launch_bounds__(256) void comb_kernel(
    const float* __restrict__ accP, const float* __restrict__ lP,
    unsigned short* __restrict__ outb, float* __restrict__ outf,
    int KS, int H, int lgHO, int do_elu)
{
    const int idx = blockIdx.x * 256 + threadIdx.x;
    const int HO = 1 << lgHO;
    const int n = idx >> lgHO, col = idx & (HO - 1), h = col >> 6;
    float s = 0.f, l = 0.f;
    for (int ks = 0; ks < KS; ++ks) {
        s += accP[((size_t)ks * 4096 + n) * HO + col];
        l += lP[((size_t)ks * H + h) * 4096 + n];
    }
    float v = s / l;
    if (do_elu && v < 0.f) v = exp2_fast(v * LOG2E) - 1.f;
    if (outf) outf[idx] = v;
    else      outb[idx] = bf16_rne(v);
}

// ---------------------------------------------------------------------------
extern "C" void kernel_launch(void* const* d_in, const int* in_sizes, int n_in,
                              void* d_out, int out_size, void* d_ws, size_t ws_size,
                              hipStream_t stream)
{
    (void)in_sizes; (void)n_in; (void)out_size; (void)ws_size;
    const float* x   = (const float*)d_in[0];
    const int*   adj = (const int*)d_in[1];
    const float* W0  = (const float*)d_in[2];
    const float* a0  = (const float*)d_in[3];
    const float* W1  = (const float*)d_in[4];
    const float* a1  = (const float*)d_in[5];
    const float* W2  = (const float*)d_in[6];
    const float* a2  = (const float*)d_in[7];

    char* p = (char*)d_ws;                                   // 15.5 MB used
    unsigned long long* bits = (unsigned long long*)(p + 0x000000);  // 2 MB
    unsigned short* hT  = (unsigned short*)(p + 0x200000);           // 2 MB
    unsigned short* X12 = (unsigned short*)(p + 0x400000);           // 2 MB
    unsigned short* Xc  = (unsigned short*)(p + 0x600000);           // 1 MB
    unsigned short* W0t = (unsigned short*)(p + 0x700000);           // 64 KB
    unsigned short* W1t = (unsigned short*)(p + 0x710000);           // 128 KB
    unsigned short* W2t = (unsigned short*)(p + 0x730000);           // 32 KB
    float*    el2  = (float*)(p + 0x738000);                         // 64 KB
    float*    er2  = (float*)(p + 0x748000);                         // 64 KB
    unsigned* MxU  = (unsigned*)(p + 0x758000);                      // 48 B
    float*    accP = (float*)(p + 0x760000);                         // 8 MB
    float*    lP   = (float*)(p + 0xF60000);                         // 128 KB

    prep_all<<<18881, 256, 0, stream>>>(x, adj, W0, W1, W2, Xc, bits,
                                        W0t, W1t, W2t, MxU);

    // layer 0: K=128, H=4
    gemm_elr<<<dim3(64, 4), 256, 0, stream>>>(Xc, 128, W0t, a0, hT, el2, er2, MxU + 0);
    att_kernel<<<dim3(64, 4, 2), 256, 0, stream>>>(hT, el2, er2, MxU + 0, bits, accP, lP, 4, 2048, 256);
    comb_kernel<<<4096, 256, 0, stream>>>(accP, lP, X12, nullptr, 2, 4, 8, 1);

    // layer 1: K=256, H=4
    gemm_elr<<<dim3(64, 4), 256, 0, stream>>>(X12, 256, W1t, a1, hT, el2, er2, MxU + 4);
    att_kernel<<<dim3(64, 4, 2), 256, 0, stream>>>(hT, el2, er2, MxU + 4, bits, accP, lP, 4, 2048, 256);
    comb_kernel<<<4096, 256, 0, stream>>>(accP, lP, X12, nullptr, 2, 4, 8, 1);

    // layer 2: K=256, H=1, output f32 (no ELU); KS=8 -> 512 blocks (2/CU)
    gemm_elr<<<dim3(64, 1), 256, 0, stream>>>(X12, 256, W2t, a2, hT, el2, er2, MxU + 8);
    att_kernel<<<dim3(64, 1, 8), 256, 0, stream>>>(hT, el2, er2, MxU + 8, bits, accP, lP, 1, 512, 64);
    comb_kernel<<<1024, 256, 0, stream>>>(accP, lP, nullptr, (float*)d_out, 8, 1, 6, 0);
}